// Round 3
// baseline (23.018 us; speedup 1.0000x reference)
//
#include <hip/hip_runtime.h>
#include <math.h>

#define N_BINS 100
#define N_CAP  2

__device__ __forceinline__ float sigmoidf(float x) {
    return 1.0f / (1.0f + expf(-x));
}

// Fused: each block computes the 200-entry LUT (cheap, hidden), then streams.
// LUT[cap*N_BINS + bin] = trust_temp(bin_centers[bin], cap); will folded into cap 0.
// Main loop unrolled 2-deep with stride-separated accesses: both loads and both
// stores are perfectly coalesced, and the two chains are independent (ILP=2).
__global__ __launch_bounds__(256) void RobotTrustModel_trust_kernel(
        const float* __restrict__ bin_centers,
        const float* __restrict__ pre_beta,
        const float* __restrict__ pre_can_l,
        const float* __restrict__ pre_can_u,
        const float* __restrict__ pre_will_l,
        const float* __restrict__ pre_will_u,
        const int4*  __restrict__ idx,
        float2*      __restrict__ out,
        int n_pairs) {
    __shared__ float slut[N_CAP * N_BINS];

    int tid = threadIdx.x;
    if (tid < N_CAP * N_BINS) {
        int cap = tid / N_BINS;
        int bin = tid % N_BINS;

        float cl_raw = fminf(pre_can_l[cap], pre_can_u[cap]);
        float cu_raw = fmaxf(pre_can_l[cap], pre_can_u[cap]);
        float can_l = sigmoidf(cl_raw);
        float can_u = sigmoidf(cu_raw);

        float wl_raw = fminf(pre_will_l[0], pre_will_u[0]);
        float wu_raw = fmaxf(pre_will_l[0], pre_will_u[0]);
        float will = 0.5f * (sigmoidf(wl_raw) + sigmoidf(wu_raw));

        float beta  = pre_beta[cap] * pre_beta[cap];
        float denom = can_u - can_l;
        float p     = bin_centers[bin];

        float t;
        if (beta < -50.0f) {
            t = 1.0f - (1.0f / (beta * denom)) *
                (log1pf(expf(beta * (p - can_l))) - log1pf(expf(beta * (p - can_u))));
        } else {
            t = (p <= can_l) ? 1.0f
              : ((p > can_u) ? 0.0f
              : (can_u - p) / (denom + 1e-4f));
        }
        if (cap == 0) t *= will;
        slut[cap * N_BINS + bin] = t;
    }
    __syncthreads();

    int gid    = blockIdx.x * blockDim.x + tid;
    int stride = gridDim.x * blockDim.x;

    int t = gid;
    for (; t + stride < n_pairs; t += 2 * stride) {
        int t2 = t + stride;
        int4 v0 = idx[t];
        int4 v1 = idx[t2];
        float2 a, b;
        a.x = slut[v0.x] * slut[N_BINS + v0.y];
        a.y = slut[v0.z] * slut[N_BINS + v0.w];
        b.x = slut[v1.x] * slut[N_BINS + v1.y];
        b.y = slut[v1.z] * slut[N_BINS + v1.w];
        out[t]  = a;
        out[t2] = b;
    }
    if (t < n_pairs) {
        int4 v0 = idx[t];
        float2 a;
        a.x = slut[v0.x] * slut[N_BINS + v0.y];
        a.y = slut[v0.z] * slut[N_BINS + v0.w];
        out[t] = a;
    }
}

extern "C" void kernel_launch(void* const* d_in, const int* in_sizes, int n_in,
                              void* d_out, int out_size, void* d_ws, size_t ws_size,
                              hipStream_t stream) {
    const float* bin_centers = (const float*)d_in[0];
    const int*   obs_idx     = (const int*)d_in[1];
    const float* pre_beta    = (const float*)d_in[2];
    const float* pre_can_l   = (const float*)d_in[3];
    const float* pre_can_u   = (const float*)d_in[4];
    const float* pre_will_l  = (const float*)d_in[5];
    const float* pre_will_u  = (const float*)d_in[6];

    float* out = (float*)d_out;

    int n_diffs = in_sizes[1] / N_CAP;       // 8388608
    int n_pairs = n_diffs / 2;               // 4194304: 2 rows per thread via int4

    int block = 256;
    int grid  = 2048;                        // 8 blocks/CU, 8 pairs/thread (4 unrolled iters)
    RobotTrustModel_trust_kernel<<<grid, block, 0, stream>>>(
        bin_centers, pre_beta, pre_can_l, pre_can_u, pre_will_l, pre_will_u,
        (const int4*)obs_idx, (float2*)out, n_pairs);
}

// Round 4
// 21.171 us; speedup vs baseline: 1.0873x; 1.0873x over previous
//
#include <hip/hip_runtime.h>
#include <math.h>

#define N_BINS 100
#define N_CAP  2

__device__ __forceinline__ float sigmoidf(float x) {
    return 1.0f / (1.0f + expf(-x));
}

// Fused: each block computes the 200-entry LUT, then streams int4 idx -> float2 out.
// Key structure: the FIRST streaming load is issued BEFORE the LUT math, so the
// parameter-load + expf preamble latency hides under it; the main loop carries a
// one-deep load-ahead register (next load issues before current compute/store).
__global__ __launch_bounds__(256) void RobotTrustModel_trust_kernel(
        const float* __restrict__ bin_centers,
        const float* __restrict__ pre_beta,
        const float* __restrict__ pre_can_l,
        const float* __restrict__ pre_can_u,
        const float* __restrict__ pre_will_l,
        const float* __restrict__ pre_will_u,
        const int4*  __restrict__ idx,
        float2*      __restrict__ out,
        int n_pairs) {
    __shared__ float slut[N_CAP * N_BINS];

    int tid    = threadIdx.x;
    int gid    = blockIdx.x * blockDim.x + tid;
    int stride = gridDim.x * blockDim.x;

    // --- issue first streaming load immediately ---
    int  t = gid;
    int4 v = make_int4(0, 0, 0, 0);
    if (t < n_pairs) v = idx[t];

    // --- LUT compute (latency hidden under the load above) ---
    if (tid < N_CAP * N_BINS) {
        int cap = tid / N_BINS;
        int bin = tid % N_BINS;

        float cl_raw = fminf(pre_can_l[cap], pre_can_u[cap]);
        float cu_raw = fmaxf(pre_can_l[cap], pre_can_u[cap]);
        float can_l = sigmoidf(cl_raw);
        float can_u = sigmoidf(cu_raw);

        float wl_raw = fminf(pre_will_l[0], pre_will_u[0]);
        float wu_raw = fmaxf(pre_will_l[0], pre_will_u[0]);
        float will = 0.5f * (sigmoidf(wl_raw) + sigmoidf(wu_raw));

        float beta  = pre_beta[cap] * pre_beta[cap];
        float denom = can_u - can_l;
        float p     = bin_centers[bin];

        float tt;
        if (beta < -50.0f) {
            tt = 1.0f - (1.0f / (beta * denom)) *
                 (log1pf(expf(beta * (p - can_l))) - log1pf(expf(beta * (p - can_u))));
        } else {
            tt = (p <= can_l) ? 1.0f
               : ((p > can_u) ? 0.0f
               : (can_u - p) / (denom + 1e-4f));
        }
        if (cap == 0) tt *= will;
        slut[cap * N_BINS + bin] = tt;
    }
    __syncthreads();

    // --- software-pipelined streaming loop ---
    while (t < n_pairs) {
        int  tn = t + stride;
        int4 vn = make_int4(0, 0, 0, 0);
        if (tn < n_pairs) vn = idx[tn];

        float2 a;
        a.x = slut[v.x] * slut[N_BINS + v.y];
        a.y = slut[v.z] * slut[N_BINS + v.w];
        out[t] = a;

        v = vn;
        t = tn;
    }
}

extern "C" void kernel_launch(void* const* d_in, const int* in_sizes, int n_in,
                              void* d_out, int out_size, void* d_ws, size_t ws_size,
                              hipStream_t stream) {
    const float* bin_centers = (const float*)d_in[0];
    const int*   obs_idx     = (const int*)d_in[1];
    const float* pre_beta    = (const float*)d_in[2];
    const float* pre_can_l   = (const float*)d_in[3];
    const float* pre_can_u   = (const float*)d_in[4];
    const float* pre_will_l  = (const float*)d_in[5];
    const float* pre_will_u  = (const float*)d_in[6];

    float* out = (float*)d_out;

    int n_diffs = in_sizes[1] / N_CAP;       // 8388608
    int n_pairs = n_diffs / 2;               // 4194304: 2 rows per thread via int4

    int block = 256;
    int grid  = 4096;                        // 4 grid-stride iters/thread (R1's best)
    RobotTrustModel_trust_kernel<<<grid, block, 0, stream>>>(
        bin_centers, pre_beta, pre_can_l, pre_can_u, pre_will_l, pre_will_u,
        (const int4*)obs_idx, (float2*)out, n_pairs);
}

// Round 5
// 20.776 us; speedup vs baseline: 1.1080x; 1.0190x over previous
//
#include <hip/hip_runtime.h>
#include <math.h>

#define N_BINS 100
#define N_CAP  2

__device__ __forceinline__ float sigmoidf(float x) {
    return 1.0f / (1.0f + expf(-x));
}

// One-shot kernel: each thread handles exactly 4 rows (2 int4 index loads,
// 8 LDS gathers, 1 float4 store). Grid sized so grid*block == n_pairs/2.
// Copy-bench access shape: 32B/lane read, 16B/lane write, no loop, no branch.
__global__ __launch_bounds__(256) void RobotTrustModel_trust_kernel(
        const float* __restrict__ bin_centers,
        const float* __restrict__ pre_beta,
        const float* __restrict__ pre_can_l,
        const float* __restrict__ pre_can_u,
        const float* __restrict__ pre_will_l,
        const float* __restrict__ pre_will_u,
        const int4*  __restrict__ idx,
        float4*      __restrict__ out,
        int n_quads) {
    __shared__ float slut[N_CAP * N_BINS];

    int tid = threadIdx.x;
    int t   = blockIdx.x * blockDim.x + tid;

    // --- issue both streaming loads immediately (preamble hides under them) ---
    int4 v0 = make_int4(0, 0, 0, 0), v1 = make_int4(0, 0, 0, 0);
    if (t < n_quads) {
        v0 = idx[2 * t];
        v1 = idx[2 * t + 1];
    }

    // --- LUT compute ---
    if (tid < N_CAP * N_BINS) {
        int cap = tid / N_BINS;
        int bin = tid % N_BINS;

        float cl_raw = fminf(pre_can_l[cap], pre_can_u[cap]);
        float cu_raw = fmaxf(pre_can_l[cap], pre_can_u[cap]);
        float can_l = sigmoidf(cl_raw);
        float can_u = sigmoidf(cu_raw);

        float wl_raw = fminf(pre_will_l[0], pre_will_u[0]);
        float wu_raw = fmaxf(pre_will_l[0], pre_will_u[0]);
        float will = 0.5f * (sigmoidf(wl_raw) + sigmoidf(wu_raw));

        float beta  = pre_beta[cap] * pre_beta[cap];
        float denom = can_u - can_l;
        float p     = bin_centers[bin];

        float tt;
        if (beta < -50.0f) {
            tt = 1.0f - (1.0f / (beta * denom)) *
                 (log1pf(expf(beta * (p - can_l))) - log1pf(expf(beta * (p - can_u))));
        } else {
            tt = (p <= can_l) ? 1.0f
               : ((p > can_u) ? 0.0f
               : (can_u - p) / (denom + 1e-4f));
        }
        if (cap == 0) tt *= will;
        slut[cap * N_BINS + bin] = tt;
    }
    __syncthreads();

    if (t < n_quads) {
        float4 r;
        r.x = slut[v0.x] * slut[N_BINS + v0.y];
        r.y = slut[v0.z] * slut[N_BINS + v0.w];
        r.z = slut[v1.x] * slut[N_BINS + v1.y];
        r.w = slut[v1.z] * slut[N_BINS + v1.w];
        out[t] = r;
    }
}

extern "C" void kernel_launch(void* const* d_in, const int* in_sizes, int n_in,
                              void* d_out, int out_size, void* d_ws, size_t ws_size,
                              hipStream_t stream) {
    const float* bin_centers = (const float*)d_in[0];
    const int*   obs_idx     = (const int*)d_in[1];
    const float* pre_beta    = (const float*)d_in[2];
    const float* pre_can_l   = (const float*)d_in[3];
    const float* pre_can_u   = (const float*)d_in[4];
    const float* pre_will_l  = (const float*)d_in[5];
    const float* pre_will_u  = (const float*)d_in[6];

    float* out = (float*)d_out;

    int n_diffs = in_sizes[1] / N_CAP;       // 8388608
    int n_quads = n_diffs / 4;               // 2097152: 4 rows per thread
    int block   = 256;
    int grid    = (n_quads + block - 1) / block;   // 8192 blocks, one-shot

    RobotTrustModel_trust_kernel<<<grid, block, 0, stream>>>(
        bin_centers, pre_beta, pre_can_l, pre_can_u, pre_will_l, pre_will_u,
        (const int4*)obs_idx, (float4*)out, n_quads);
}